// Round 13
// baseline (284.725 us; speedup 1.0000x reference)
//
#include <hip/hip_runtime.h>

#define NGRAPH 1000
#define P      100
#define EPG    1200
#define INF    16
#define HID    64
#define NOUT   5

#define ASTR   68    // A row stride (17 granules, odd -> full bank spread)
#define TSTR   20    // merged T row stride (5 granules, odd -> full bank spread)
                     //   T1 = cols 0..7, T2 = cols 8..15 (both 16B aligned)
#define NPAD   112   // 16 uniform groups * 7 nodes (rows 100..111 = don't-care)

// LDS: A 112*68*4=30464 + TT 112*20*4=8960 + csr_off 404 + dinv 448
//      = 40,276 B -> 4 blocks/CU.  csr_src lives in d_ws (global, L1-resident
//      on re-reads) -> frees LDS capacity AND moves index loads off the
//      saturated LDS pipe onto the idle VMEM pipe.
//      d_ws usage: NGRAPH * 1280 u16 = 2.56 MB.
//
// HARD RULES (r6..r11 lessons):
//  - every loop touching acc[] is #pragma unroll, compile-time trip, no guards
//  - allocator pins 64 VGPRs and spills above; keep peak pressure < 64
//  - do NOT hand-unroll the gather edge loop (r11: -16%)
//  - T stride must be odd-granule: stride-8 rows have only 8 bank positions
//    -> structural ~8-way gather conflicts (r12 counter: 1.16e7)

__device__ __forceinline__ void fma4(float4& a, float s, const float4 w) {
    a.x += s * w.x; a.y += s * w.y; a.z += s * w.z; a.w += s * w.w;
}

// Gather one 8-column slice into TT[n*TSTR + doff .. +8) from CSR (prescaled).
// isX2=0: D = -dinv[n]^2 * sum_e S[s]
// isX2=1: D = -2*dinv[n]^2 * sum_e S[s] - A0[n*ASTR + aoff]
__device__ __forceinline__ void prop8(
    const float* __restrict__ S, int sstride, int soff,
    float* __restrict__ TT, int doff,
    const float* __restrict__ A0, int aoff, int isX2,
    const unsigned short* __restrict__ gsrc,   // global CSR edge sources
    const int* __restrict__ csr_off,
    const float* __restrict__ dinv,
    int tid)
{
    const int q = tid & 1;        // feature quad within slice
    const int n = tid >> 1;       // node (128 slots >= 100)
    if (n < P) {
        const int kb = csr_off[n], ke = csr_off[n + 1];
        float ax = 0.f, ay = 0.f, az = 0.f, aw = 0.f;
        for (int k = kb; k < ke; k++) {
            int s = gsrc[k];
            const float4 x = *(const float4*)&S[s * sstride + soff + q * 4];
            ax += x.x; ay += x.y; az += x.z; aw += x.w;
        }
        float dn = dinv[n];
        float d2 = dn * dn;
        float4 o;
        if (!isX2) {
            float m = -d2;
            o.x = m * ax; o.y = m * ay; o.z = m * az; o.w = m * aw;
        } else {
            float m = -2.f * d2;
            const float4 y0 = *(const float4*)&A0[n * ASTR + aoff + q * 4];
            o.x = m * ax - y0.x; o.y = m * ay - y0.y;
            o.z = m * az - y0.z; o.w = m * aw - y0.w;
        }
        *(float4*)&TT[n * TSTR + doff + q * 4] = o;
    }
}

// One ChebConv(K=3) layer in prescaled form: A (Y, F cols) -> A (Y or H).
// Matmul thread: cq4=(tid&15)*4 cols, 7 uniform nodes n0=(tid>>4)*7.
template <int F, int FINAL>
__device__ __forceinline__ void cheb_layer(
    float* __restrict__ A, float* __restrict__ TT,
    const unsigned short* __restrict__ gsrc,
    const int* __restrict__ csr_off,
    const float* __restrict__ dinv,
    const float* __restrict__ W, const float* __restrict__ bias,
    int tid)
{
    const int cq4 = (tid & 15) * 4;
    const int n0  = (tid >> 4) * 7;

    float4 acc[7];
#pragma unroll
    for (int i = 0; i < 7; i++) acc[i] = make_float4(0.f, 0.f, 0.f, 0.f);

    for (int cb = 0; cb < F; cb += 8) {
        // X1-gather: A-slice -> TT cols 0..7
        prop8(A, ASTR, cb, TT, 0, (const float*)0, 0, 0,
              gsrc, csr_off, dinv, tid);
        __syncthreads();
        // X2-gather: TT cols 0..7 -> TT cols 8..15 (disjoint columns, safe)
        prop8(TT, TSTR, 0, TT, 8, A, cb, 1,
              gsrc, csr_off, dinv, tid);
        __syncthreads();

        // partial matmul over this 8-feature slice, 3 sections (Y0, Y1, Y2)
        for (int sec = 0; sec < 3; sec++) {
            const float* xp; int xstr, xoff, wrow0;
            if (sec == 0)      { xp = A;  xstr = ASTR; xoff = cb; wrow0 = cb; }
            else if (sec == 1) { xp = TT; xstr = TSTR; xoff = 0;  wrow0 = F + cb; }
            else               { xp = TT; xstr = TSTR; xoff = 8;  wrow0 = 2 * F + cb; }
            for (int j4 = 0; j4 < 8; j4 += 4) {
                const float4 w0 = *(const float4*)&W[(wrow0 + j4 + 0) * HID + cq4];
                const float4 w1 = *(const float4*)&W[(wrow0 + j4 + 1) * HID + cq4];
                const float4 w2 = *(const float4*)&W[(wrow0 + j4 + 2) * HID + cq4];
                const float4 w3 = *(const float4*)&W[(wrow0 + j4 + 3) * HID + cq4];
                const float* xb = xp + n0 * xstr + xoff + j4;
#pragma unroll
                for (int i = 0; i < 7; i++) {
                    const float4 x = *(const float4*)&xb[i * xstr];
                    fma4(acc[i], x.x, w0); fma4(acc[i], x.y, w1);
                    fma4(acc[i], x.z, w2); fma4(acc[i], x.w, w3);
                }
            }
        }
        __syncthreads();   // TT (and A-slice) reads done before next overwrite
    }

    // Epilogue (pad rows get don't-care values; no guard):
    //  FINAL=0: A = relu(acc + dinv[n]*b)   (stores Y = dinv*H)
    //  FINAL=1: A = relu(acc/dinv[n] + b)   (stores H; pool reads H directly)
    const float4 bv = *(const float4*)&bias[cq4];
#pragma unroll
    for (int i = 0; i < 7; i++) {
        float dn = dinv[n0 + i];
        float4 o;
        if (FINAL) {
            float sd = 1.0f / dn;
            o.x = fmaxf(acc[i].x * sd + bv.x, 0.f);
            o.y = fmaxf(acc[i].y * sd + bv.y, 0.f);
            o.z = fmaxf(acc[i].z * sd + bv.z, 0.f);
            o.w = fmaxf(acc[i].w * sd + bv.w, 0.f);
        } else {
            o.x = fmaxf(acc[i].x + bv.x * dn, 0.f);
            o.y = fmaxf(acc[i].y + bv.y * dn, 0.f);
            o.z = fmaxf(acc[i].z + bv.z * dn, 0.f);
            o.w = fmaxf(acc[i].w + bv.w * dn, 0.f);
        }
        *(float4*)&A[(n0 + i) * ASTR + cq4] = o;
    }
    __syncthreads();
}

__global__ __launch_bounds__(256, 4) void gnn_kernel(
    const float* __restrict__ feat,
    const int* __restrict__ src, const int* __restrict__ dst,
    const float* __restrict__ W1, const float* __restrict__ b1,
    const float* __restrict__ W2, const float* __restrict__ b2,
    const float* __restrict__ W3, const float* __restrict__ b3,
    const float* __restrict__ Wfc, const float* __restrict__ bfc,
    unsigned short* __restrict__ ws_csr,   // NGRAPH*1280 u16 in d_ws
    float* __restrict__ out)
{
    __shared__ __align__(16) float A[NPAD * ASTR];
    __shared__ __align__(16) float TT[NPAD * TSTR];
    __shared__ int   csr_off[P + 1];
    __shared__ float dinv[NPAD];   // rows 100..111 = 1.0 (keeps pad rows finite)

    const int g = blockIdx.x;
    const int tid = threadIdx.x;
    const int base = g * P;
    const int* srcg = src + g * EPG;
    const int* dstg = dst + g * EPG;
    unsigned short* gsrc = ws_csr + (size_t)g * 1280;

    int* deg = (int*)TT;         // aliased; consumed before layer 1
    int* cur = ((int*)TT) + P;   // aliased; consumed before layer 1

    // ---- degree count ----
    for (int i = tid; i < P; i += 256) deg[i] = 0;
    __syncthreads();
    for (int e = tid; e < EPG; e += 256) {
        int d = dstg[e] - base;
        atomicAdd(&deg[d], 1);
    }
    __syncthreads();

    // ---- dinv + serial prefix scan (both read deg) ----
    for (int i = tid; i < NPAD; i += 256) {
        if (i < P) {
            int dg = deg[i] > 1 ? deg[i] : 1;
            dinv[i] = rsqrtf((float)dg);
        } else {
            dinv[i] = 1.0f;
        }
    }
    if (tid == 0) {
        int run = 0;
        csr_off[0] = 0;
        for (int i = 0; i < P; i++) { run += deg[i]; csr_off[i + 1] = run; }
    }
    __syncthreads();

    // ---- feat load prescaled (A = dinv*feat) + CSR cursor init ----
    for (int i = tid; i < P * INF / 4; i += 256) {
        int n = i >> 2, fq = (i & 3) * 4;
        float4 v = *(const float4*)&feat[(size_t)base * INF + i * 4];
        float dn = dinv[n];
        v.x *= dn; v.y *= dn; v.z *= dn; v.w *= dn;
        *(float4*)&A[n * ASTR + fq] = v;
    }
    for (int i = tid; i < P; i += 256) cur[i] = csr_off[i];
    __syncthreads();
    // ---- CSR fill (edge sources to global ws) ----
    for (int e = tid; e < EPG; e += 256) {
        int s = srcg[e] - base;
        int d = dstg[e] - base;
        int pos = atomicAdd(&cur[d], 1);
        gsrc[pos] = (unsigned short)s;
    }
    __syncthreads();

    // ---- 3 ChebConv layers (prescaled; final layer emits H) ----
    cheb_layer<INF, 0>(A, TT, gsrc, csr_off, dinv, W1, b1, tid);
    cheb_layer<HID, 0>(A, TT, gsrc, csr_off, dinv, W2, b2, tid);
    cheb_layer<HID, 1>(A, TT, gsrc, csr_off, dinv, W3, b3, tid);

    // ---- mean pool + FC (TT as scratch: 320 floats <= 2240) ----
    {
        const int lane = tid & 63, w = tid >> 6;
        float s = 0.f;
        for (int n = w; n < P; n += 4) s += A[n * ASTR + lane];
        TT[w * 64 + lane] = s;
    }
    __syncthreads();
    if (tid < HID) {
        float hg = (TT[tid] + TT[64 + tid] + TT[128 + tid] + TT[192 + tid]) * (1.0f / P);
        TT[256 + tid] = hg;
    }
    __syncthreads();
    if (tid < NOUT) {
        float o = bfc[tid];
        for (int c = 0; c < HID; c++) o += TT[256 + c] * Wfc[c * NOUT + tid];
        out[g * NOUT + tid] = o;
    }
}

extern "C" void kernel_launch(void* const* d_in, const int* in_sizes, int n_in,
                              void* d_out, int out_size, void* d_ws, size_t ws_size,
                              hipStream_t stream)
{
    const float* feat = (const float*)d_in[0];
    const int*   src  = (const int*)d_in[1];
    const int*   dst  = (const int*)d_in[2];
    const float* W1  = (const float*)d_in[5];
    const float* b1  = (const float*)d_in[6];
    const float* W2  = (const float*)d_in[7];
    const float* b2  = (const float*)d_in[8];
    const float* W3  = (const float*)d_in[9];
    const float* b3  = (const float*)d_in[10];
    const float* Wfc = (const float*)d_in[11];
    const float* bfc = (const float*)d_in[12];
    float* out = (float*)d_out;

    gnn_kernel<<<NGRAPH, 256, 0, stream>>>(feat, src, dst,
                                           W1, b1, W2, b2, W3, b3, Wfc, bfc,
                                           (unsigned short*)d_ws, out);
}

// Round 14
// 245.343 us; speedup vs baseline: 1.1605x; 1.1605x over previous
//
#include <hip/hip_runtime.h>

#define NGRAPH 1000
#define P      100
#define EPG    1200
#define INF    16
#define HID    64
#define NOUT   5

#define ASTR   84    // unified row stride: 21 granules (odd) -> 8-start-bank
                     // class (optimal for 16B-aligned rows) for ALL accesses.
                     // Row layout: cols 0..63 = Y activations, 64..71 = T1
                     // (X1 slice), 72..79 = T2 (X2 slice), 80..83 pad.
#define T1OFF  64
#define T2OFF  72
#define NPAD   112   // 16 uniform groups * 7 nodes (rows 100..111 don't-care)

// LDS: A 112*84*4=37632 + dinv 448 + csr_off 404 + csr_src 2400 = 40,884 B
//      -> 40,960 block -> 4 blocks/CU.  deg/cursor alias A's pad rows.
//
// HARD RULES (r6..r13 lessons):
//  - every loop touching acc[] is #pragma unroll, compile-time trip, no guards
//  - allocator pins 64 VGPRs, spills above; keep peak pressure < 64
//  - do NOT hand-unroll the gather edge loop (r11: -16%)
//  - csr_src stays in LDS (r13: global u16 index loads add VMEM latency to
//    the serial edge walk, -27%)
//  - aligned-f4 rows have at most 8 bank-start positions; stride/4 odd mod 8
//    achieves it. Stride-8 rows (4 positions) double gather pileup (r12 T).

__device__ __forceinline__ void fma4(float4& a, float s, const float4 w) {
    a.x += s * w.x; a.y += s * w.y; a.z += s * w.z; a.w += s * w.w;
}

// Gather one 8-column slice within the unified A buffer (prescaled form).
// Reads A[s][soff..soff+7], writes A[n][doff..doff+7].
// isX2=0: D = -dinv[n]^2 * sum_e S[s]
// isX2=1: D = -2*dinv[n]^2 * sum_e S[s] - A[n][aoff..]
__device__ __forceinline__ void prop8(
    float* __restrict__ A, int soff, int doff, int aoff, int isX2,
    const unsigned short* __restrict__ csr_src,
    const int* __restrict__ csr_off,
    const float* __restrict__ dinv,
    int tid)
{
    const int q = tid & 1;        // feature quad within slice
    const int n = tid >> 1;       // node (128 slots >= 100)
    if (n < P) {
        const int kb = csr_off[n], ke = csr_off[n + 1];
        float ax = 0.f, ay = 0.f, az = 0.f, aw = 0.f;
        for (int k = kb; k < ke; k++) {
            int s = csr_src[k];
            const float4 x = *(const float4*)&A[s * ASTR + soff + q * 4];
            ax += x.x; ay += x.y; az += x.z; aw += x.w;
        }
        float dn = dinv[n];
        float d2 = dn * dn;
        float4 o;
        if (!isX2) {
            float m = -d2;
            o.x = m * ax; o.y = m * ay; o.z = m * az; o.w = m * aw;
        } else {
            float m = -2.f * d2;
            const float4 y0 = *(const float4*)&A[n * ASTR + aoff + q * 4];
            o.x = m * ax - y0.x; o.y = m * ay - y0.y;
            o.z = m * az - y0.z; o.w = m * aw - y0.w;
        }
        *(float4*)&A[n * ASTR + doff + q * 4] = o;
    }
}

// One ChebConv(K=3) layer in prescaled form: A cols 0..F-1 (Y) -> cols 0..63.
// Matmul thread: cq4=(tid&15)*4 cols, 7 uniform nodes n0=(tid>>4)*7.
template <int F, int FINAL>
__device__ __forceinline__ void cheb_layer(
    float* __restrict__ A,
    const unsigned short* __restrict__ csr_src,
    const int* __restrict__ csr_off,
    const float* __restrict__ dinv,
    const float* __restrict__ W, const float* __restrict__ bias,
    int tid)
{
    const int cq4 = (tid & 15) * 4;
    const int n0  = (tid >> 4) * 7;

    float4 acc[7];
#pragma unroll
    for (int i = 0; i < 7; i++) acc[i] = make_float4(0.f, 0.f, 0.f, 0.f);

    for (int cb = 0; cb < F; cb += 8) {
        // X1-gather: Y slice cb -> T1 (cols 64..71); col-disjoint, race-free
        prop8(A, cb, T1OFF, 0, 0, csr_src, csr_off, dinv, tid);
        __syncthreads();
        // X2-gather: T1 -> T2 (cols 72..79), minus Y slice cb
        prop8(A, T1OFF, T2OFF, cb, 1, csr_src, csr_off, dinv, tid);
        __syncthreads();

        // partial matmul over this 8-feature slice, 3 sections (Y0, Y1, Y2)
        for (int sec = 0; sec < 3; sec++) {
            int xoff, wrow0;
            if (sec == 0)      { xoff = cb;    wrow0 = cb; }
            else if (sec == 1) { xoff = T1OFF; wrow0 = F + cb; }
            else               { xoff = T2OFF; wrow0 = 2 * F + cb; }
            for (int j4 = 0; j4 < 8; j4 += 4) {
                const float4 w0 = *(const float4*)&W[(wrow0 + j4 + 0) * HID + cq4];
                const float4 w1 = *(const float4*)&W[(wrow0 + j4 + 1) * HID + cq4];
                const float4 w2 = *(const float4*)&W[(wrow0 + j4 + 2) * HID + cq4];
                const float4 w3 = *(const float4*)&W[(wrow0 + j4 + 3) * HID + cq4];
                const float* xb = A + n0 * ASTR + xoff + j4;
#pragma unroll
                for (int i = 0; i < 7; i++) {
                    const float4 x = *(const float4*)&xb[i * ASTR];
                    fma4(acc[i], x.x, w0); fma4(acc[i], x.y, w1);
                    fma4(acc[i], x.z, w2); fma4(acc[i], x.w, w3);
                }
            }
        }
        __syncthreads();   // all T1/T2/A-slice reads done before next overwrite
    }

    // Epilogue (pad rows get don't-care values; no guard):
    //  FINAL=0: A = relu(acc + dinv[n]*b)   (stores Y = dinv*H)
    //  FINAL=1: A = relu(acc/dinv[n] + b)   (stores H; pool reads H directly)
    const float4 bv = *(const float4*)&bias[cq4];
#pragma unroll
    for (int i = 0; i < 7; i++) {
        float dn = dinv[n0 + i];
        float4 o;
        if (FINAL) {
            float sd = 1.0f / dn;
            o.x = fmaxf(acc[i].x * sd + bv.x, 0.f);
            o.y = fmaxf(acc[i].y * sd + bv.y, 0.f);
            o.z = fmaxf(acc[i].z * sd + bv.z, 0.f);
            o.w = fmaxf(acc[i].w * sd + bv.w, 0.f);
        } else {
            o.x = fmaxf(acc[i].x + bv.x * dn, 0.f);
            o.y = fmaxf(acc[i].y + bv.y * dn, 0.f);
            o.z = fmaxf(acc[i].z + bv.z * dn, 0.f);
            o.w = fmaxf(acc[i].w + bv.w * dn, 0.f);
        }
        *(float4*)&A[(n0 + i) * ASTR + cq4] = o;
    }
    __syncthreads();
}

__global__ __launch_bounds__(256, 4) void gnn_kernel(
    const float* __restrict__ feat,
    const int* __restrict__ src, const int* __restrict__ dst,
    const float* __restrict__ W1, const float* __restrict__ b1,
    const float* __restrict__ W2, const float* __restrict__ b2,
    const float* __restrict__ W3, const float* __restrict__ b3,
    const float* __restrict__ Wfc, const float* __restrict__ bfc,
    float* __restrict__ out)
{
    __shared__ __align__(16) float A[NPAD * ASTR];
    __shared__ float dinv[NPAD];   // rows 100..111 = 1.0 (pad rows stay finite)
    __shared__ int   csr_off[P + 1];
    __shared__ unsigned short csr_src[EPG];

    const int g = blockIdx.x;
    const int tid = threadIdx.x;
    const int base = g * P;
    const int* srcg = src + g * EPG;
    const int* dstg = dst + g * EPG;

    // deg / CSR cursor live in A's pad-row area (rows 100..111 = 4032 B);
    // consumed before any pad-row write (first pad write: layer-1 epilogue).
    int* deg = (int*)&A[P * ASTR];
    int* cur = deg + 128;

    // ---- degree count ----
    for (int i = tid; i < P; i += 256) deg[i] = 0;
    __syncthreads();
    for (int e = tid; e < EPG; e += 256) {
        int d = dstg[e] - base;
        atomicAdd(&deg[d], 1);
    }
    __syncthreads();

    // ---- dinv + serial prefix scan (both read deg) ----
    for (int i = tid; i < NPAD; i += 256) {
        if (i < P) {
            int dg = deg[i] > 1 ? deg[i] : 1;
            dinv[i] = rsqrtf((float)dg);
        } else {
            dinv[i] = 1.0f;
        }
    }
    if (tid == 0) {
        int run = 0;
        csr_off[0] = 0;
        for (int i = 0; i < P; i++) { run += deg[i]; csr_off[i + 1] = run; }
    }
    __syncthreads();

    // ---- feat load prescaled (A = dinv*feat) + CSR cursor init ----
    for (int i = tid; i < P * INF / 4; i += 256) {
        int n = i >> 2, fq = (i & 3) * 4;
        float4 v = *(const float4*)&feat[(size_t)base * INF + i * 4];
        float dn = dinv[n];
        v.x *= dn; v.y *= dn; v.z *= dn; v.w *= dn;
        *(float4*)&A[n * ASTR + fq] = v;
    }
    for (int i = tid; i < P; i += 256) cur[i] = csr_off[i];
    __syncthreads();
    // ---- CSR fill (LDS) ----
    for (int e = tid; e < EPG; e += 256) {
        int s = srcg[e] - base;
        int d = dstg[e] - base;
        int pos = atomicAdd(&cur[d], 1);
        csr_src[pos] = (unsigned short)s;
    }
    __syncthreads();

    // ---- 3 ChebConv layers (prescaled; final layer emits H) ----
    cheb_layer<INF, 0>(A, csr_src, csr_off, dinv, W1, b1, tid);
    cheb_layer<HID, 0>(A, csr_src, csr_off, dinv, W2, b2, tid);
    cheb_layer<HID, 1>(A, csr_src, csr_off, dinv, W3, b3, tid);

    // ---- mean pool + FC (reuse T1/T2 cols of row region via dinv? no —
    //      use A pad-row area as scratch: 320 floats <= 1008 pad floats) ----
    float* psum = &A[P * ASTR];   // pad rows; layer outputs there are dead
    {
        const int lane = tid & 63, w = tid >> 6;
        float s = 0.f;
        for (int n = w; n < P; n += 4) s += A[n * ASTR + lane];
        __syncthreads();          // pad-row garbage reads done (none) / reuse safe
        psum[w * 64 + lane] = s;
    }
    __syncthreads();
    if (tid < HID) {
        float hg = (psum[tid] + psum[64 + tid] + psum[128 + tid] + psum[192 + tid]) * (1.0f / P);
        psum[256 + tid] = hg;
    }
    __syncthreads();
    if (tid < NOUT) {
        float o = bfc[tid];
        for (int c = 0; c < HID; c++) o += psum[256 + c] * Wfc[c * NOUT + tid];
        out[g * NOUT + tid] = o;
    }
}

extern "C" void kernel_launch(void* const* d_in, const int* in_sizes, int n_in,
                              void* d_out, int out_size, void* d_ws, size_t ws_size,
                              hipStream_t stream)
{
    const float* feat = (const float*)d_in[0];
    const int*   src  = (const int*)d_in[1];
    const int*   dst  = (const int*)d_in[2];
    const float* W1  = (const float*)d_in[5];
    const float* b1  = (const float*)d_in[6];
    const float* W2  = (const float*)d_in[7];
    const float* b2  = (const float*)d_in[8];
    const float* W3  = (const float*)d_in[9];
    const float* b3  = (const float*)d_in[10];
    const float* Wfc = (const float*)d_in[11];
    const float* bfc = (const float*)d_in[12];
    float* out = (float*)d_out;

    gnn_kernel<<<NGRAPH, 256, 0, stream>>>(feat, src, dst,
                                           W1, b1, W2, b2, W3, b3, Wfc, bfc, out);
}

// Round 15
// 233.568 us; speedup vs baseline: 1.2190x; 1.0504x over previous
//
#include <hip/hip_runtime.h>

#define NGRAPH 1000
#define P      100
#define EPG    1200
#define INF    16
#define HID    64
#define NOUT   5

#define ASTR   88    // unified row: cols 0..63 Y, 64..71 T1a, 72..79 T2,
                     // 80..87 T1b. Even-granule stride is fine: r13/r14
                     // proved bank conflicts are NOT the bottleneck.
#define T2OFF  72
#define SLOTA  64
#define SLOTB  80
#define NPAD   104   // 8 node-groups * 13 rows (rows 100..103 don't-care pad)

// LDS: A 104*88*4=36608 + dinv 416 + csr_off 404 + csr_src 2400 = 39,828 B
//      -> 4 blocks/CU.  deg/cursor alias A's pad rows (consumed pre-layer-1).
//
// HARD RULES (r6..r14 lessons):
//  - every loop touching acc[] is #pragma unroll, compile-time trip, no guards
//  - allocator pins 64 VGPRs, spills above; keep peak pressure < 64
//  - keep gather loop body SIMPLE (r11: hand-unroll -16%); csr_src in LDS (r13)
//  - conflicts don't matter (r13/r14); WALK COUNT does: this round fuses
//    X2(cb) with X1(cb+8) into ONE edge walk (shared index, two b128 chains,
//    ping-pong T1) -> 36 walks/block -> 21.

__device__ __forceinline__ float4 f4fma(float4 a, float m, float4 x) {
    a.x += m * x.x; a.y += m * x.y; a.z += m * x.z; a.w += m * x.w; return a;
}

// Prologue gather: T1[dslot] = -dinv^2 * sum_e Y[s][soff..+7]   (X1 of slice 0)
__device__ __forceinline__ void prop_x1(
    float* __restrict__ A, int soff, int dslot,
    const unsigned short* __restrict__ csr_src,
    const int* __restrict__ csr_off,
    const float* __restrict__ dinv, int tid)
{
    const int q4 = (tid & 1) * 4;
    const int n  = tid >> 1;
    if (n < P) {
        const int kb = csr_off[n], ke = csr_off[n + 1];
        float ax = 0.f, ay = 0.f, az = 0.f, aw = 0.f;
        for (int k = kb; k < ke; k++) {
            int s = csr_src[k];
            const float4 x = *(const float4*)&A[s * ASTR + soff + q4];
            ax += x.x; ay += x.y; az += x.z; aw += x.w;
        }
        float dn = dinv[n];
        float m = -dn * dn;
        float4 o; o.x = m * ax; o.y = m * ay; o.z = m * az; o.w = m * aw;
        *(float4*)&A[n * ASTR + dslot + q4] = o;
    }
}

// Fused dual gather, ONE edge walk:
//   T2      = -2*dinv^2 * sum_e A[s][t1c..]  -  Y[n][ycur..]     (X2 of cb)
//   T1[t1n] =   -dinv^2 * sum_e A[s][ynext..]                    (X1 of cb+8)
// pre (block-uniform): whether the X1-prefetch part is active.
__device__ __forceinline__ void prop_dual(
    float* __restrict__ A, int t1c, int t1n, int ycur, int ynext, bool pre,
    const unsigned short* __restrict__ csr_src,
    const int* __restrict__ csr_off,
    const float* __restrict__ dinv, int tid)
{
    const int q4 = (tid & 1) * 4;
    const int n  = tid >> 1;
    if (n < P) {
        const int kb = csr_off[n], ke = csr_off[n + 1];
        float4 a2 = make_float4(0.f, 0.f, 0.f, 0.f);
        float4 a1 = make_float4(0.f, 0.f, 0.f, 0.f);
        if (pre) {
            for (int k = kb; k < ke; k++) {
                int s = csr_src[k];
                const float* rp = &A[s * ASTR + q4];
                const float4 x2 = *(const float4*)&rp[t1c];
                const float4 x1 = *(const float4*)&rp[ynext];
                a2.x += x2.x; a2.y += x2.y; a2.z += x2.z; a2.w += x2.w;
                a1.x += x1.x; a1.y += x1.y; a1.z += x1.z; a1.w += x1.w;
            }
        } else {
            for (int k = kb; k < ke; k++) {
                int s = csr_src[k];
                const float4 x2 = *(const float4*)&A[s * ASTR + t1c + q4];
                a2.x += x2.x; a2.y += x2.y; a2.z += x2.z; a2.w += x2.w;
            }
        }
        float dn = dinv[n];
        float d2 = dn * dn;
        const float4 y0 = *(const float4*)&A[n * ASTR + ycur + q4];
        float4 o2;
        float m2 = -2.f * d2;
        o2.x = m2 * a2.x - y0.x; o2.y = m2 * a2.y - y0.y;
        o2.z = m2 * a2.z - y0.z; o2.w = m2 * a2.w - y0.w;
        *(float4*)&A[n * ASTR + T2OFF + q4] = o2;
        if (pre) {
            float m1 = -d2;
            float4 o1;
            o1.x = m1 * a1.x; o1.y = m1 * a1.y;
            o1.z = m1 * a1.z; o1.w = m1 * a1.w;
            *(float4*)&A[n * ASTR + t1n + q4] = o1;
        }
    }
}

// mm section: acc[13](float2) += X[n0..n0+12][8 feats] @ W[., c2..c2+1].
__device__ __forceinline__ void mm_sec(
    const float* __restrict__ A, int xoff,
    const float* __restrict__ W, int wrow0,
    int c2, int n0, float2 (&acc)[13])
{
    for (int j4 = 0; j4 < 8; j4 += 4) {
        const float2 w0 = *(const float2*)&W[(wrow0 + j4 + 0) * HID + c2];
        const float2 w1 = *(const float2*)&W[(wrow0 + j4 + 1) * HID + c2];
        const float2 w2 = *(const float2*)&W[(wrow0 + j4 + 2) * HID + c2];
        const float2 w3 = *(const float2*)&W[(wrow0 + j4 + 3) * HID + c2];
        const float* xb = A + n0 * ASTR + xoff + j4;
#pragma unroll
        for (int i = 0; i < 13; i++) {
            const float4 x = *(const float4*)&xb[i * ASTR];
            acc[i].x += x.x * w0.x + x.y * w1.x + x.z * w2.x + x.w * w3.x;
            acc[i].y += x.x * w0.y + x.y * w1.y + x.z * w2.y + x.w * w3.y;
        }
    }
}

// One ChebConv(K=3) layer, prescaled form: A cols 0..F-1 (Y) -> cols 0..63.
template <int F, int FINAL>
__device__ __forceinline__ void cheb_layer(
    float* __restrict__ A,
    const unsigned short* __restrict__ csr_src,
    const int* __restrict__ csr_off,
    const float* __restrict__ dinv,
    const float* __restrict__ W, const float* __restrict__ bias,
    int tid)
{
    const int c2 = (tid & 31) * 2;   // 2 output cols
    const int n0 = (tid >> 5) * 13;  // 13 nodes (8 groups cover 104 rows)

    float2 acc[13];
#pragma unroll
    for (int i = 0; i < 13; i++) acc[i] = make_float2(0.f, 0.f);

    // prologue: X1 of slice 0 -> SLOTA
    prop_x1(A, 0, SLOTA, csr_src, csr_off, dinv, tid);
    __syncthreads();

    int t1c = SLOTA, t1n = SLOTB;
    for (int cb = 0; cb < F; cb += 8) {
        const bool pre = (cb + 8 < F);
        // fused gather: X2(cb) -> T2, X1(cb+8) -> t1n (one edge walk)
        prop_dual(A, t1c, t1n, cb, cb + 8, pre, csr_src, csr_off, dinv, tid);
        __syncthreads();
        // matmul over this 8-feature slice, 3 sections
        mm_sec(A, cb,    W, cb,         c2, n0, acc);
        mm_sec(A, t1c,   W, F + cb,     c2, n0, acc);
        mm_sec(A, T2OFF, W, 2 * F + cb, c2, n0, acc);
        __syncthreads();   // reads of t1c/T2/Y-slice done before next gather
        int t = t1c; t1c = t1n; t1n = t;
    }

    // Epilogue (pad rows 100..103 get don't-care values; no guard):
    //  FINAL=0: A = relu(acc + dinv[n]*b)   (stores Y = dinv*H)
    //  FINAL=1: A = relu(acc/dinv[n] + b)   (stores H; pool reads H directly)
    const float2 bv = *(const float2*)&bias[c2];
#pragma unroll
    for (int i = 0; i < 13; i++) {
        float dn = dinv[n0 + i];
        float2 o;
        if (FINAL) {
            float sd = 1.0f / dn;
            o.x = fmaxf(acc[i].x * sd + bv.x, 0.f);
            o.y = fmaxf(acc[i].y * sd + bv.y, 0.f);
        } else {
            o.x = fmaxf(acc[i].x + bv.x * dn, 0.f);
            o.y = fmaxf(acc[i].y + bv.y * dn, 0.f);
        }
        *(float2*)&A[(n0 + i) * ASTR + c2] = o;
    }
    __syncthreads();
}

__global__ __launch_bounds__(256, 4) void gnn_kernel(
    const float* __restrict__ feat,
    const int* __restrict__ src, const int* __restrict__ dst,
    const float* __restrict__ W1, const float* __restrict__ b1,
    const float* __restrict__ W2, const float* __restrict__ b2,
    const float* __restrict__ W3, const float* __restrict__ b3,
    const float* __restrict__ Wfc, const float* __restrict__ bfc,
    float* __restrict__ out)
{
    __shared__ __align__(16) float A[NPAD * ASTR];
    __shared__ float dinv[NPAD];   // rows 100..103 = 1.0
    __shared__ int   csr_off[P + 1];
    __shared__ unsigned short csr_src[EPG];

    const int g = blockIdx.x;
    const int tid = threadIdx.x;
    const int base = g * P;
    const int* srcg = src + g * EPG;
    const int* dstg = dst + g * EPG;

    // deg / cursor live in A's pad rows (rows 100..103 = 352 floats);
    // consumed before the first pad-row write (layer-1 epilogue).
    int* deg = (int*)&A[P * ASTR];
    int* cur = deg + 128;

    // ---- degree count ----
    for (int i = tid; i < P; i += 256) deg[i] = 0;
    __syncthreads();
    for (int e = tid; e < EPG; e += 256) {
        int d = dstg[e] - base;
        atomicAdd(&deg[d], 1);
    }
    __syncthreads();

    // ---- dinv + serial prefix scan ----
    for (int i = tid; i < NPAD; i += 256) {
        if (i < P) {
            int dg = deg[i] > 1 ? deg[i] : 1;
            dinv[i] = rsqrtf((float)dg);
        } else {
            dinv[i] = 1.0f;
        }
    }
    if (tid == 0) {
        int run = 0;
        csr_off[0] = 0;
        for (int i = 0; i < P; i++) { run += deg[i]; csr_off[i + 1] = run; }
    }
    __syncthreads();

    // ---- feat load prescaled (A = dinv*feat) + CSR cursor init ----
    for (int i = tid; i < P * INF / 4; i += 256) {
        int n = i >> 2, fq = (i & 3) * 4;
        float4 v = *(const float4*)&feat[(size_t)base * INF + i * 4];
        float dn = dinv[n];
        v.x *= dn; v.y *= dn; v.z *= dn; v.w *= dn;
        *(float4*)&A[n * ASTR + fq] = v;
    }
    for (int i = tid; i < P; i += 256) cur[i] = csr_off[i];
    __syncthreads();
    // ---- CSR fill (LDS) ----
    for (int e = tid; e < EPG; e += 256) {
        int s = srcg[e] - base;
        int d = dstg[e] - base;
        int pos = atomicAdd(&cur[d], 1);
        csr_src[pos] = (unsigned short)s;
    }
    __syncthreads();

    // ---- 3 ChebConv layers (prescaled; final layer emits H) ----
    cheb_layer<INF, 0>(A, csr_src, csr_off, dinv, W1, b1, tid);
    cheb_layer<HID, 0>(A, csr_src, csr_off, dinv, W2, b2, tid);
    cheb_layer<HID, 1>(A, csr_src, csr_off, dinv, W3, b3, tid);

    // ---- mean pool + FC (pad-row area as scratch: 320 <= 352 floats) ----
    float* psum = &A[P * ASTR];
    {
        const int lane = tid & 63, w = tid >> 6;
        float s = 0.f;
        for (int n = w; n < P; n += 4) s += A[n * ASTR + lane];
        __syncthreads();
        psum[w * 64 + lane] = s;
    }
    __syncthreads();
    if (tid < HID) {
        float hg = (psum[tid] + psum[64 + tid] + psum[128 + tid] + psum[192 + tid]) * (1.0f / P);
        psum[256 + tid] = hg;
    }
    __syncthreads();
    if (tid < NOUT) {
        float o = bfc[tid];
        for (int c = 0; c < HID; c++) o += psum[256 + c] * Wfc[c * NOUT + tid];
        out[g * NOUT + tid] = o;
    }
}

extern "C" void kernel_launch(void* const* d_in, const int* in_sizes, int n_in,
                              void* d_out, int out_size, void* d_ws, size_t ws_size,
                              hipStream_t stream)
{
    const float* feat = (const float*)d_in[0];
    const int*   src  = (const int*)d_in[1];
    const int*   dst  = (const int*)d_in[2];
    const float* W1  = (const float*)d_in[5];
    const float* b1  = (const float*)d_in[6];
    const float* W2  = (const float*)d_in[7];
    const float* b2  = (const float*)d_in[8];
    const float* W3  = (const float*)d_in[9];
    const float* b3  = (const float*)d_in[10];
    const float* Wfc = (const float*)d_in[11];
    const float* bfc = (const float*)d_in[12];
    float* out = (float*)d_out;

    gnn_kernel<<<NGRAPH, 256, 0, stream>>>(feat, src, dst,
                                           W1, b1, W2, b2, W3, b3, Wfc, bfc, out);
}

// Round 16
// 191.416 us; speedup vs baseline: 1.4875x; 1.2202x over previous
//
#include <hip/hip_runtime.h>

#define NGRAPH 1000
#define P      100
#define EPG    1200
#define INF    16
#define HID    64
#define NOUT   5

#define ASTR   88    // unified row: cols 0..63 Y, 64..71 T1a, 72..79 T2, 80..87 T1b
#define T2OFF  72
#define SLOTA  64
#define SLOTB  80
#define NPAD   112   // 7 MFMA row-tiles x 16; rows 100..111 = pad/metadata

// LDS: A 112*88*4 = 39,424 + csr_src(u8) 1,200 = 40,624 B -> 4 blocks/CU.
// deg/cur/csr_off/dinv/psum live in A's pad rows (floats 8800..9856):
//   deg @8800(100 int), cur @8900(100 int), csr_off @9000(101 int),
//   dinv @9104(100 f32), psum @9204(320 f32).
// Tile-6 A-frags read pad rows as garbage -> only D rows >=100 (discarded).
// Epilogue stores are guarded row<100, so metadata survives the layers.
//
// HARD RULES (r6..r15): acc arrays only with compile-time unrolled indices;
// gather loop stays simple (r11); csr indices in LDS (r13); conflicts and
// walk count are secondary (r13-r15). This round: matmul -> MFMA bf16 hi/lo
// split (err ~2^-16, threshold 1.13e-3). Gather phases byte-identical to r15.

typedef short short8 __attribute__((ext_vector_type(8)));
typedef float f32x4  __attribute__((ext_vector_type(4)));

__device__ __forceinline__ void bsplit(float x, short& h, short& l) {
    unsigned u = __float_as_uint(x);
    h = (short)(u >> 16);
    float hf = __uint_as_float(u & 0xffff0000u);
    l = (short)(__float_as_uint(x - hf) >> 16);
}

// ---- gather phase (verbatim r15 dataflow, u8 indices) ----
__device__ __forceinline__ void prop_x1(
    float* __restrict__ A, int soff, int dslot,
    const unsigned char* __restrict__ csr_src,
    const int* __restrict__ csr_off,
    const float* __restrict__ dinv, int tid)
{
    const int q4 = (tid & 1) * 4;
    const int n  = tid >> 1;
    if (n < P) {
        const int kb = csr_off[n], ke = csr_off[n + 1];
        float ax = 0.f, ay = 0.f, az = 0.f, aw = 0.f;
        for (int k = kb; k < ke; k++) {
            int s = csr_src[k];
            const float4 x = *(const float4*)&A[s * ASTR + soff + q4];
            ax += x.x; ay += x.y; az += x.z; aw += x.w;
        }
        float dn = dinv[n];
        float m = -dn * dn;
        float4 o; o.x = m * ax; o.y = m * ay; o.z = m * az; o.w = m * aw;
        *(float4*)&A[n * ASTR + dslot + q4] = o;
    }
}

__device__ __forceinline__ void prop_dual(
    float* __restrict__ A, int t1c, int t1n, int ycur, int ynext, bool pre,
    const unsigned char* __restrict__ csr_src,
    const int* __restrict__ csr_off,
    const float* __restrict__ dinv, int tid)
{
    const int q4 = (tid & 1) * 4;
    const int n  = tid >> 1;
    if (n < P) {
        const int kb = csr_off[n], ke = csr_off[n + 1];
        float4 a2 = make_float4(0.f, 0.f, 0.f, 0.f);
        float4 a1 = make_float4(0.f, 0.f, 0.f, 0.f);
        if (pre) {
            for (int k = kb; k < ke; k++) {
                int s = csr_src[k];
                const float* rp = &A[s * ASTR + q4];
                const float4 x2 = *(const float4*)&rp[t1c];
                const float4 x1 = *(const float4*)&rp[ynext];
                a2.x += x2.x; a2.y += x2.y; a2.z += x2.z; a2.w += x2.w;
                a1.x += x1.x; a1.y += x1.y; a1.z += x1.z; a1.w += x1.w;
            }
        } else {
            for (int k = kb; k < ke; k++) {
                int s = csr_src[k];
                const float4 x2 = *(const float4*)&A[s * ASTR + t1c + q4];
                a2.x += x2.x; a2.y += x2.y; a2.z += x2.z; a2.w += x2.w;
            }
        }
        float dn = dinv[n];
        float d2 = dn * dn;
        const float4 y0 = *(const float4*)&A[n * ASTR + ycur + q4];
        float4 o2;
        float m2 = -2.f * d2;
        o2.x = m2 * a2.x - y0.x; o2.y = m2 * a2.y - y0.y;
        o2.z = m2 * a2.z - y0.z; o2.w = m2 * a2.w - y0.w;
        *(float4*)&A[n * ASTR + T2OFF + q4] = o2;
        if (pre) {
            float m1 = -d2;
            float4 o1;
            o1.x = m1 * a1.x; o1.y = m1 * a1.y;
            o1.z = m1 * a1.z; o1.w = m1 * a1.w;
            *(float4*)&A[n * ASTR + t1n + q4] = o1;
        }
    }
}

// ---- one ChebConv layer: gather (r15) + MFMA matmul (bf16 split) ----
template <int F, int FINAL>
__device__ __forceinline__ void cheb_layer(
    float* __restrict__ A,
    const unsigned char* __restrict__ csr_src,
    const int* __restrict__ csr_off,
    const float* __restrict__ dinv,
    const float* __restrict__ W, const float* __restrict__ bias,
    int tid)
{
    const int lane = tid & 63;
    const int wv   = tid >> 6;          // wave = col-tile (cols wv*16..+15)
    const int n16  = lane & 15;
    const int q    = lane >> 4;         // K-quad: 0=Y(cb) 1=T1 2=T2 3=zero
    const int ncol = (wv << 4) + n16;
    const float qsc = (q < 3) ? 1.f : 0.f;

    f32x4 acc[7];
#pragma unroll
    for (int t = 0; t < 7; t++) { acc[t][0]=0.f; acc[t][1]=0.f; acc[t][2]=0.f; acc[t][3]=0.f; }

    prop_x1(A, 0, SLOTA, csr_src, csr_off, dinv, tid);
    __syncthreads();

    int t1c = SLOTA, t1n = SLOTB;
    for (int cb = 0; cb < F; cb += 8) {
        const bool pre = (cb + 8 < F);
        prop_dual(A, t1c, t1n, cb, cb + 8, pre, csr_src, csr_off, dinv, tid);
        __syncthreads();

        // B fragment: W rows per K-quad {cb, F+cb, 2F+cb, dummy}, col = ncol
        const int wrow = (q == 0) ? cb : (q == 1) ? (F + cb)
                       : (q == 2) ? (2 * F + cb) : cb;
        short8 bhi, blo;
#pragma unroll
        for (int j = 0; j < 8; j++) {
            float b = W[(wrow + j) * HID + ncol] * qsc;
            short h, l; bsplit(b, h, l);
            bhi[j] = h; blo[j] = l;
        }
        const int aoff = (q == 0) ? cb : (q == 1) ? t1c
                       : (q == 2) ? T2OFF : cb;
#pragma unroll
        for (int t = 0; t < 7; t++) {
            const float* xp = &A[(t * 16 + n16) * ASTR + aoff];
            const float4 v0 = *(const float4*)xp;
            const float4 v1 = *(const float4*)(xp + 4);
            short8 ahi, alo; short h, l;
            bsplit(v0.x * qsc, h, l); ahi[0] = h; alo[0] = l;
            bsplit(v0.y * qsc, h, l); ahi[1] = h; alo[1] = l;
            bsplit(v0.z * qsc, h, l); ahi[2] = h; alo[2] = l;
            bsplit(v0.w * qsc, h, l); ahi[3] = h; alo[3] = l;
            bsplit(v1.x * qsc, h, l); ahi[4] = h; alo[4] = l;
            bsplit(v1.y * qsc, h, l); ahi[5] = h; alo[5] = l;
            bsplit(v1.z * qsc, h, l); ahi[6] = h; alo[6] = l;
            bsplit(v1.w * qsc, h, l); ahi[7] = h; alo[7] = l;
            acc[t] = __builtin_amdgcn_mfma_f32_16x16x32_bf16(ahi, bhi, acc[t], 0, 0, 0);
            acc[t] = __builtin_amdgcn_mfma_f32_16x16x32_bf16(ahi, blo, acc[t], 0, 0, 0);
            acc[t] = __builtin_amdgcn_mfma_f32_16x16x32_bf16(alo, bhi, acc[t], 0, 0, 0);
        }
        __syncthreads();
        int tt = t1c; t1c = t1n; t1n = tt;
    }

    // Epilogue: D layout col=lane&15, row=(lane>>4)*4+reg (m89-verified).
    // Store guard row<P keeps pad-row metadata intact.
    const float bcol = bias[ncol];
    const int rbase = q * 4;
#pragma unroll
    for (int t = 0; t < 7; t++) {
#pragma unroll
        for (int r = 0; r < 4; r++) {
            int row = t * 16 + rbase + r;
            if (row < P) {
                float dn = dinv[row];
                float v = acc[t][r];
                float o;
                if (FINAL) o = fmaxf(v * (1.0f / dn) + bcol, 0.f);
                else       o = fmaxf(v + bcol * dn, 0.f);
                A[row * ASTR + ncol] = o;
            }
        }
    }
    __syncthreads();
}

__global__ __launch_bounds__(256, 4) void gnn_kernel(
    const float* __restrict__ feat,
    const int* __restrict__ src, const int* __restrict__ dst,
    const float* __restrict__ W1, const float* __restrict__ b1,
    const float* __restrict__ W2, const float* __restrict__ b2,
    const float* __restrict__ W3, const float* __restrict__ b3,
    const float* __restrict__ Wfc, const float* __restrict__ bfc,
    float* __restrict__ out)
{
    __shared__ __align__(16) float A[NPAD * ASTR];
    __shared__ unsigned char csr_src[EPG];

    const int g = blockIdx.x;
    const int tid = threadIdx.x;
    const int base = g * P;
    const int* srcg = src + g * EPG;
    const int* dstg = dst + g * EPG;

    // metadata embedded in A's pad rows (floats 8800..9856)
    int*   deg     = (int*)&A[P * ASTR];          // 8800
    int*   cur     = (int*)&A[P * ASTR + 100];    // 8900
    int*   csr_off = (int*)&A[P * ASTR + 200];    // 9000 (101 ints)
    float* dinv    = &A[P * ASTR + 304];          // 9104 (100 f32)
    float* psum    = &A[P * ASTR + 404];          // 9204 (320 f32)

    // ---- degree count ----
    for (int i = tid; i < P; i += 256) deg[i] = 0;
    __syncthreads();
    for (int e = tid; e < EPG; e += 256) {
        int d = dstg[e] - base;
        atomicAdd(&deg[d], 1);
    }
    __syncthreads();

    // ---- dinv + serial prefix scan ----
    for (int i = tid; i < P; i += 256) {
        int dg = deg[i] > 1 ? deg[i] : 1;
        dinv[i] = rsqrtf((float)dg);
    }
    if (tid == 0) {
        int run = 0;
        csr_off[0] = 0;
        for (int i = 0; i < P; i++) { run += deg[i]; csr_off[i + 1] = run; }
    }
    __syncthreads();

    // ---- feat load prescaled (A = dinv*feat) + CSR cursor init ----
    for (int i = tid; i < P * INF / 4; i += 256) {
        int n = i >> 2, fq = (i & 3) * 4;
        float4 v = *(const float4*)&feat[(size_t)base * INF + i * 4];
        float dn = dinv[n];
        v.x *= dn; v.y *= dn; v.z *= dn; v.w *= dn;
        *(float4*)&A[n * ASTR + fq] = v;
    }
    for (int i = tid; i < P; i += 256) cur[i] = csr_off[i];
    __syncthreads();
    // ---- CSR fill (u8 node ids, LDS) ----
    for (int e = tid; e < EPG; e += 256) {
        int s = srcg[e] - base;
        int d = dstg[e] - base;
        int pos = atomicAdd(&cur[d], 1);
        csr_src[pos] = (unsigned char)s;
    }
    __syncthreads();

    // ---- 3 ChebConv layers (prescaled; final layer emits H) ----
    cheb_layer<INF, 0>(A, csr_src, csr_off, dinv, W1, b1, tid);
    cheb_layer<HID, 0>(A, csr_src, csr_off, dinv, W2, b2, tid);
    cheb_layer<HID, 1>(A, csr_src, csr_off, dinv, W3, b3, tid);

    // ---- mean pool + FC ----
    {
        const int lane = tid & 63, w = tid >> 6;
        float s = 0.f;
        for (int n = w; n < P; n += 4) s += A[n * ASTR + lane];
        psum[w * 64 + lane] = s;
    }
    __syncthreads();
    if (tid < HID) {
        float hg = (psum[tid] + psum[64 + tid] + psum[128 + tid] + psum[192 + tid]) * (1.0f / P);
        psum[256 + tid] = hg;
    }
    __syncthreads();
    if (tid < NOUT) {
        float o = bfc[tid];
        for (int c = 0; c < HID; c++) o += psum[256 + c] * Wfc[c * NOUT + tid];
        out[g * NOUT + tid] = o;
    }
}

extern "C" void kernel_launch(void* const* d_in, const int* in_sizes, int n_in,
                              void* d_out, int out_size, void* d_ws, size_t ws_size,
                              hipStream_t stream)
{
    const float* feat = (const float*)d_in[0];
    const int*   src  = (const int*)d_in[1];
    const int*   dst  = (const int*)d_in[2];
    const float* W1  = (const float*)d_in[5];
    const float* b1  = (const float*)d_in[6];
    const float* W2  = (const float*)d_in[7];
    const float* b2  = (const float*)d_in[8];
    const float* W3  = (const float*)d_in[9];
    const float* b3  = (const float*)d_in[10];
    const float* Wfc = (const float*)d_in[11];
    const float* bfc = (const float*)d_in[12];
    float* out = (float*)d_out;

    gnn_kernel<<<NGRAPH, 256, 0, stream>>>(feat, src, dst,
                                           W1, b1, W2, b2, W3, b3, Wfc, bfc, out);
}